// Round 4
// baseline (377.531 us; speedup 1.0000x reference)
//
#include <hip/hip_runtime.h>

typedef unsigned int u32;

// JAX PRNG flavor: 1 = threefry_partitionable (default since jax 0.4.36), 0 = original.
// Round-3 evidence: TF_PART=1 produced ZERO false positives vs reference -> correct flavor.
#define TF_PART 1
#define NA_MAX 64

// workspace byte offsets (total ~6.6 MB)
#define META_OFF 0
#define CNT_OFF  1024
#define SK_OFF   4096
#define KEYS_OFF 16384
#define MASK_OFF (KEYS_OFF + 131072)
#define PNA_OFF  (MASK_OFF + 131072)
#define SUMA_OFF (PNA_OFF + 32 * 64 * 768 * 4)

// ---------------- threefry2x32 (matches jax._src.prng.threefry2x32) ----------------
__device__ __forceinline__ void tf2x32(u32 k0, u32 k1, u32 x0, u32 x1, u32& o0, u32& o1) {
  const u32 ks2 = k0 ^ k1 ^ 0x1BD11BDAu;
  u32 v0 = x0 + k0, v1 = x1 + k1;
#define TFR(r) { v0 += v1; v1 = (v1 << (r)) | (v1 >> (32 - (r))); v1 ^= v0; }
  TFR(13) TFR(15) TFR(26) TFR(6)   v0 += k1;  v1 += ks2 + 1u;
  TFR(17) TFR(29) TFR(16) TFR(24)  v0 += ks2; v1 += k0 + 2u;
  TFR(13) TFR(15) TFR(26) TFR(6)   v0 += k0;  v1 += k1 + 3u;
  TFR(17) TFR(29) TFR(16) TFR(24)  v0 += k1;  v1 += ks2 + 4u;
  TFR(13) TFR(15) TFR(26) TFR(6)   v0 += ks2; v1 += k0 + 5u;
#undef TFR
  o0 = v0; o1 = v1;
}

__device__ __forceinline__ float bits_to_unit(u32 b) {
  // jax.random.uniform: bitcast((bits>>9)|0x3f800000) - 1.0
  return __uint_as_float((b >> 9) | 0x3f800000u) - 1.0f;
}

// ---------------- K0a: meta (na, k_add), permutation sort-keys -> global, zero counters ----
// Why thr is NOT computed anywhere: sim[l,l] = ||pn_l||^2 = 1 +- ~1e-5 in fp32, and every
// bsearch midpoint is <= 1 - 2^-10, so any(sim>thr,axis=-1) is all-true, ratio==1 at every
// step, diff constant => best_t locks to the FIRST midpoint. thr == 0.5 for any target<1.
__global__ void k0a_setup(const int* __restrict__ pct, int* __restrict__ meta,
                          int* __restrict__ cnt, u32* __restrict__ sk_g) {
  __shared__ u32 sub0, sub1;
  const int t = threadIdx.x;
  if (t == 0) {
    u32 ka0, ka1, kb0, kb1, s0, s1;
#if TF_PART
    tf2x32(0u, 42u, 0u, 0u, ka0, ka1);   // k_anchor = split(key(42))[0]
    tf2x32(0u, 42u, 0u, 1u, kb0, kb1);   // k_add    = split(key(42))[1]
    tf2x32(ka0, ka1, 0u, 1u, s0, s1);    // shuffle subkey = split(k_anchor)[1]
#else
    u32 a, b, c, d;
    tf2x32(0u, 42u, 0u, 2u, a, b);
    tf2x32(0u, 42u, 1u, 3u, c, d);
    ka0 = a; ka1 = c; kb0 = b; kb1 = d;   // rows of reshape(2,2)
    tf2x32(ka0, ka1, 0u, 2u, a, b);
    tf2x32(ka0, ka1, 1u, 3u, c, d);
    s0 = b; s1 = d;                       // subkey = row 1
#endif
    meta[1] = (int)kb0; meta[2] = (int)kb1;
    sub0 = s0; sub1 = s1;
    const int p = pct[0];
    const double mr = (double)p / 100.0;
    int na = (int)(1024.0 * mr * 0.05);   // int(L * mask_ratio * 0.05)
    if (na < 1) na = 1;
    if (na > NA_MAX) na = NA_MAX;
    meta[0] = na;
  }
  if (t < 32) cnt[t] = 0;                 // per-image mask counters (ws is poisoned 0xAA)
  __syncthreads();
  // jax.random.permutation(k, 1024): ONE round (ceil(3*ln(1024)/ln(2^32-1)) == 1) of
  // stable sort_key_val(random_bits(subkey, (1024,)), arange(1024)).
#if TF_PART
  {
    u32 o0, o1;
    tf2x32(sub0, sub1, 0u, (u32)t, o0, o1);
    sk_g[t] = o0 ^ o1;
  }
#else
  if (t < 512) {
    u32 o0, o1;
    tf2x32(sub0, sub1, (u32)t, (u32)(t + 512), o0, o1);
    sk_g[t] = o0; sk_g[t + 512] = o1;
  }
#endif
}

// ---------------- K0b: stable rank of sort-keys -> anchor index set (16 blocks x 64) ------
// permutation[:na] = {t : rank(t) < na}; any(...) over anchors is order-invariant, so only
// the anchor SET matters. Loop address is wave-uniform -> scalarizable, L2-hot (4 KB).
__global__ void k0b_rank(const int* __restrict__ meta, const u32* __restrict__ sk_g,
                         int* __restrict__ meta_anchor) {
  const int t = blockIdx.x * 64 + threadIdx.x;
  const u32 mine = sk_g[t];
  const int na = meta[0];
  int rank = 0;
#pragma unroll 8
  for (int m = 0; m < 1024; ++m) {
    const u32 o = sk_g[m];
    rank += (o < mine || (o == mine && m < t)) ? 1 : 0;
  }
  if (rank < na) meta_anchor[rank] = t;
}

// ---------------- K1: keys_u = uniform(k_add, (32,1024)) -> ws ----------------
__global__ void k1_keys(const int* __restrict__ meta, float* __restrict__ keys) {
  const int i = blockIdx.x * 256 + threadIdx.x;
  const u32 k0 = (u32)meta[1], k1 = (u32)meta[2];
  u32 o0, o1;
#if TF_PART
  tf2x32(k0, k1, 0u, (u32)i, o0, o1);
  keys[i] = bits_to_unit(o0 ^ o1);
#else
  tf2x32(k0, k1, (u32)i, (u32)(i + 16384), o0, o1);
  keys[i] = bits_to_unit(o0);
  keys[i + 16384] = bits_to_unit(o1);
#endif
}

// ---------------- patch load ----------------
// Element order here is (c,py,px); reference patchify is (py,px,c). Harmless: K2 stores pnA
// and K3 loads patches with the SAME permutation and all uses (mean/ssq/dot) are
// permutation-invariant; |off-diag sim|<~0.2 vs thr=0.5 dwarfs fp32 association error.
__device__ __forceinline__ void load_patch(const float* __restrict__ img, int n, int ph, int pw,
                                           int lane, float4 v[3]) {
  const int py = lane >> 2;
  const int px = (lane & 3) << 2;
  const float* b = img + (size_t)n * 786432 + (size_t)(ph * 16 + py) * 512 + pw * 16 + px;
#pragma unroll
  for (int c = 0; c < 3; ++c)
    v[c] = *reinterpret_cast<const float4*>(b + (size_t)c * 262144);
}

__device__ __forceinline__ float wred(float v) {
#pragma unroll
  for (int k = 32; k >= 1; k >>= 1) v += __shfl_xor(v, k);
  return v;
}

// reduce 4 per-lane partials -> value for group g = lane>>4 (replicated in its 16 lanes)
__device__ __forceinline__ float red4(float a0, float a1, float a2, float a3, int lane) {
  a0 += __shfl_xor(a0, 32); a0 += __shfl_xor(a0, 16);
  a1 += __shfl_xor(a1, 32); a1 += __shfl_xor(a1, 16);
  a2 += __shfl_xor(a2, 32); a2 += __shfl_xor(a2, 16);
  a3 += __shfl_xor(a3, 32); a3 += __shfl_xor(a3, 16);
  const int g = lane >> 4;
  float v = g == 0 ? a0 : (g == 1 ? a1 : (g == 2 ? a2 : a3));
  v += __shfl_xor(v, 8);
  v += __shfl_xor(v, 4);
  v += __shfl_xor(v, 2);
  v += __shfl_xor(v, 1);
  return v;
}

__device__ __forceinline__ float dot4(float4 a, float4 b) {
  return a.x * b.x + a.y * b.y + a.z * b.z + a.w * b.w;
}
__device__ __forceinline__ float sum4(float4 a) { return a.x + a.y + a.z + a.w; }

// ---------------- K2: normalize anchor patches -> pnA, sumA ----------------
// pn = (v-mu)/||v-mu||: the reference's (std+1e-6) scale cancels exactly under L2-normalize.
__global__ void k2_anchor(const float* __restrict__ img, const int* __restrict__ meta,
                          float* __restrict__ pnA, float* __restrict__ sumA) {
  const int lane = threadIdx.x & 63;
  const int wg = blockIdx.x * 4 + (threadIdx.x >> 6);
  const int n = wg >> 6, a = wg & 63;
  const int na = meta[0];
  if (a >= na) return;
  const int m = meta[4 + a];
  const int ph = m >> 5, pw = m & 31;
  float4 v[3];
  load_patch(img, n, ph, pw, lane, v);
  float s = sum4(v[0]) + sum4(v[1]) + sum4(v[2]);
  s = wred(s);
  const float mu = s * (1.0f / 768.0f);
  float q = 0.0f;
#pragma unroll
  for (int c = 0; c < 3; ++c) {
    float dx = v[c].x - mu; q += dx * dx;
    dx = v[c].y - mu; q += dx * dx;
    dx = v[c].z - mu; q += dx * dx;
    dx = v[c].w - mu; q += dx * dx;
  }
  q = wred(q);
  const float inv = 1.0f / sqrtf(q);
  float sa = 0.0f;
  float4 o[3];
#pragma unroll
  for (int c = 0; c < 3; ++c) {
    o[c].x = (v[c].x - mu) * inv; sa += o[c].x;
    o[c].y = (v[c].y - mu) * inv; sa += o[c].y;
    o[c].z = (v[c].z - mu) * inv; sa += o[c].z;
    o[c].w = (v[c].w - mu) * inv; sa += o[c].w;
  }
  sa = wred(sa);
  float4* dst = reinterpret_cast<float4*>(pnA) + (size_t)(n * 64 + a) * 192;
  dst[lane] = o[0]; dst[lane + 64] = o[1]; dst[lane + 128] = o[2];
  if (lane == 0) sumA[n * 64 + a] = sa;
}

// ---------------- K3: anchor-sim + mask + per-image count. wave = 4 patches ---------------
// sim(a,m) = (dot(pnA_a, raw_m) - mu_m * sum(pnA_a)) / ||raw_m - mu_m||  -> img read ONCE.
__global__ __launch_bounds__(256) void k3_sim(const float* __restrict__ img, const int* __restrict__ meta,
                                              const float* __restrict__ pnA, const float* __restrict__ sumA,
                                              int* __restrict__ mask, int* __restrict__ cnt) {
  const int lane = threadIdx.x & 63;
  const int gw = blockIdx.x * 4 + (threadIdx.x >> 6);
  const int m0 = gw * 4;
  const int n = m0 >> 10;
  const int mb = m0 & 1023;
  const int ph = mb >> 5, pw0 = mb & 31;
  float4 pv[4][3];
#pragma unroll
  for (int p = 0; p < 4; ++p) load_patch(img, n, ph, pw0 + p, lane, pv[p]);

  float s0 = sum4(pv[0][0]) + sum4(pv[0][1]) + sum4(pv[0][2]);
  float s1 = sum4(pv[1][0]) + sum4(pv[1][1]) + sum4(pv[1][2]);
  float s2 = sum4(pv[2][0]) + sum4(pv[2][1]) + sum4(pv[2][2]);
  float s3 = sum4(pv[3][0]) + sum4(pv[3][1]) + sum4(pv[3][2]);
  float sv = red4(s0, s1, s2, s3, lane);
  const float mu0 = __shfl(sv, 0) * (1.0f / 768.0f);
  const float mu1 = __shfl(sv, 16) * (1.0f / 768.0f);
  const float mu2 = __shfl(sv, 32) * (1.0f / 768.0f);
  const float mu3 = __shfl(sv, 48) * (1.0f / 768.0f);
  float q0 = 0, q1 = 0, q2 = 0, q3 = 0;
#pragma unroll
  for (int c = 0; c < 3; ++c) {
    float d;
    d = pv[0][c].x - mu0; q0 += d * d; d = pv[0][c].y - mu0; q0 += d * d;
    d = pv[0][c].z - mu0; q0 += d * d; d = pv[0][c].w - mu0; q0 += d * d;
    d = pv[1][c].x - mu1; q1 += d * d; d = pv[1][c].y - mu1; q1 += d * d;
    d = pv[1][c].z - mu1; q1 += d * d; d = pv[1][c].w - mu1; q1 += d * d;
    d = pv[2][c].x - mu2; q2 += d * d; d = pv[2][c].y - mu2; q2 += d * d;
    d = pv[2][c].z - mu2; q2 += d * d; d = pv[2][c].w - mu2; q2 += d * d;
    d = pv[3][c].x - mu3; q3 += d * d; d = pv[3][c].y - mu3; q3 += d * d;
    d = pv[3][c].z - mu3; q3 += d * d; d = pv[3][c].w - mu3; q3 += d * d;
  }
  float qv = red4(q0, q1, q2, q3, lane);
  const int g = lane >> 4;
  const float invg = 1.0f / sqrtf(qv);
  const float mug = g == 0 ? mu0 : (g == 1 ? mu1 : (g == 2 ? mu2 : mu3));

  const int na = meta[0];
  int fl = 0;
  for (int a = 0; a < na; ++a) {
    const float4* A = reinterpret_cast<const float4*>(pnA) + (size_t)(n * 64 + a) * 192;
    const float4 a0 = A[lane], a1 = A[lane + 64], a2 = A[lane + 128];
    float d0 = dot4(a0, pv[0][0]) + dot4(a1, pv[0][1]) + dot4(a2, pv[0][2]);
    float d1 = dot4(a0, pv[1][0]) + dot4(a1, pv[1][1]) + dot4(a2, pv[1][2]);
    float d2 = dot4(a0, pv[2][0]) + dot4(a1, pv[2][1]) + dot4(a2, pv[2][2]);
    float d3 = dot4(a0, pv[3][0]) + dot4(a1, pv[3][1]) + dot4(a2, pv[3][2]);
    const float dv = red4(d0, d1, d2, d3, lane);
    const float sim = (dv - mug * sumA[n * 64 + a]) * invg;
    fl |= (sim > 0.5f) ? 1 : 0;
  }
  const bool leader = (lane & 15) == 0;
  if (leader) mask[n * 1024 + mb + g] = fl;
  // per-image mask count: one atomic per wave
  int v = leader ? fl : 0;
  v += __shfl_xor(v, 16);
  v += __shfl_xor(v, 32);
  if (lane == 0) atomicAdd(&cnt[n], v);
}

// ---------------- K4: stable rank of masked keys + final mask (128 blocks x 256) ----------
// Output dtype is INT32 (reference returns bool -> harness reads np.int32). Round-3 failure
// was exactly this: wrote 1.0f (bits 1065353216) vs expected integer 1.
__global__ void k4_final(const int* __restrict__ mask, const float* __restrict__ keys,
                         const int* __restrict__ cnt, int* __restrict__ out) {
  const int n = blockIdx.x >> 2;
  const int l = ((blockIdx.x & 3) << 8) + threadIdx.x;
  const int base = n * 1024;
  const int gi = base + l;
  const float INF = __int_as_float(0x7f800000);
  const int mk = mask[gi];
  const float kl = mk ? INF : keys[gi];
  const int c = cnt[n];
  // floor((0.5 - c/1024)*1024) == 512 - c exactly (dyadic values, fp32-exact)
  const int nadd = c < 512 ? (512 - c) : 0;
  int rank = 0;
#pragma unroll 4
  for (int m = 0; m < 1024; ++m) {
    const float km = mask[base + m] ? INF : keys[base + m];
    rank += (km < kl || (km == kl && m < l)) ? 1 : 0;  // stable argsort rank
  }
  out[gi] = (mk || rank < nadd) ? 1 : 0;
}

extern "C" void kernel_launch(void* const* d_in, const int* in_sizes, int n_in,
                              void* d_out, int out_size, void* d_ws, size_t ws_size,
                              hipStream_t stream) {
  const float* img = (const float*)d_in[0];
  const int* pct = (const int*)d_in[1];
  char* ws = (char*)d_ws;
  int* meta = (int*)(ws + META_OFF);
  int* cnt = (int*)(ws + CNT_OFF);
  u32* sk_g = (u32*)(ws + SK_OFF);
  float* keys = (float*)(ws + KEYS_OFF);
  int* mask = (int*)(ws + MASK_OFF);
  float* pnA = (float*)(ws + PNA_OFF);
  float* sumA = (float*)(ws + SUMA_OFF);
  int* out = (int*)d_out;

  hipLaunchKernelGGL(k0a_setup, dim3(1), dim3(1024), 0, stream, pct, meta, cnt, sk_g);
  hipLaunchKernelGGL(k0b_rank, dim3(16), dim3(64), 0, stream, meta, sk_g, meta + 4);
#if TF_PART
  hipLaunchKernelGGL(k1_keys, dim3(128), dim3(256), 0, stream, meta, keys);
#else
  hipLaunchKernelGGL(k1_keys, dim3(64), dim3(256), 0, stream, meta, keys);
#endif
  hipLaunchKernelGGL(k2_anchor, dim3(512), dim3(256), 0, stream, img, meta, pnA, sumA);
  hipLaunchKernelGGL(k3_sim, dim3(2048), dim3(256), 0, stream, img, meta, pnA, sumA, mask, cnt);
  hipLaunchKernelGGL(k4_final, dim3(128), dim3(256), 0, stream, mask, keys, cnt, out);
}

// Round 5
// 222.215 us; speedup vs baseline: 1.6989x; 1.6989x over previous
//
#include <hip/hip_runtime.h>

typedef unsigned int u32;
typedef __attribute__((ext_vector_type(8))) short bf16x8;   // 8 bf16 = 4 VGPR (guide-verified)
typedef __attribute__((ext_vector_type(4))) float f32x4;

// JAX PRNG flavor: 1 = threefry_partitionable. Round-3/4 evidence: bit-exact. Keep 1.
#define TF_PART 1

// workspace byte offsets (total ~3.3 MB)
#define META_OFF 0                         // int: [0]=na, [1..2]=k_add, [4..67]=anchor idx
#define SK_OFF   4096                      // u32 sk[1024]
#define MASK_OFF 16384                     // int mask[32*1024] = 128 KB
#define SUMA_OFF (MASK_OFF + 131072)       // float sumA[32][64]
#define FRAG_OFF (SUMA_OFF + 32*64*4)      // bf16 fragA[(n*4+mt)*24+kk][64 lanes][8] = 3 MB

// ---------------- threefry2x32 (matches jax._src.prng.threefry2x32) ----------------
__device__ __forceinline__ void tf2x32(u32 k0, u32 k1, u32 x0, u32 x1, u32& o0, u32& o1) {
  const u32 ks2 = k0 ^ k1 ^ 0x1BD11BDAu;
  u32 v0 = x0 + k0, v1 = x1 + k1;
#define TFR(r) { v0 += v1; v1 = (v1 << (r)) | (v1 >> (32 - (r))); v1 ^= v0; }
  TFR(13) TFR(15) TFR(26) TFR(6)   v0 += k1;  v1 += ks2 + 1u;
  TFR(17) TFR(29) TFR(16) TFR(24)  v0 += ks2; v1 += k0 + 2u;
  TFR(13) TFR(15) TFR(26) TFR(6)   v0 += k0;  v1 += k1 + 3u;
  TFR(17) TFR(29) TFR(16) TFR(24)  v0 += k1;  v1 += ks2 + 4u;
  TFR(13) TFR(15) TFR(26) TFR(6)   v0 += ks2; v1 += k0 + 5u;
#undef TFR
  o0 = v0; o1 = v1;
}

__device__ __forceinline__ float bits_to_unit(u32 b) {
  return __uint_as_float((b >> 9) | 0x3f800000u) - 1.0f;
}

__device__ __forceinline__ ushort f2bf(float f) {   // RNE fp32->bf16
  u32 b = __float_as_uint(f);
  return (ushort)((b + 0x7fffu + ((b >> 16) & 1u)) >> 16);
}

// ---------------- K0a: meta (na, k_add) + permutation sort-keys -> global ----------------
// thr is NOT computed: sim[l,l]=||pn_l||^2=1 in fp32 and all bsearch midpoints <1 =>
// ratio==1 every step => best_t = first midpoint = 0.5 for any target.
__global__ void k0a_setup(const int* __restrict__ pct, int* __restrict__ meta,
                          u32* __restrict__ sk_g) {
  __shared__ u32 sub0, sub1;
  const int t = threadIdx.x;
  if (t == 0) {
    u32 ka0, ka1, kb0, kb1, s0, s1;
#if TF_PART
    tf2x32(0u, 42u, 0u, 0u, ka0, ka1);   // k_anchor = split(key(42))[0]
    tf2x32(0u, 42u, 0u, 1u, kb0, kb1);   // k_add    = split(key(42))[1]
    tf2x32(ka0, ka1, 0u, 1u, s0, s1);    // shuffle subkey = split(k_anchor)[1]
#else
    u32 a, b, c, d;
    tf2x32(0u, 42u, 0u, 2u, a, b);
    tf2x32(0u, 42u, 1u, 3u, c, d);
    ka0 = a; ka1 = c; kb0 = b; kb1 = d;
    tf2x32(ka0, ka1, 0u, 2u, a, b);
    tf2x32(ka0, ka1, 1u, 3u, c, d);
    s0 = b; s1 = d;
#endif
    meta[1] = (int)kb0; meta[2] = (int)kb1;
    sub0 = s0; sub1 = s1;
    const int p = pct[0];
    int na = (int)(1024.0 * ((double)p / 100.0) * 0.05);  // int(L*mask_ratio*0.05)
    if (na < 1) na = 1;
    if (na > 64) na = 64;
    meta[0] = na;
  }
  __syncthreads();
#if TF_PART
  { u32 o0, o1; tf2x32(sub0, sub1, 0u, (u32)t, o0, o1); sk_g[t] = o0 ^ o1; }
#else
  if (t < 512) {
    u32 o0, o1; tf2x32(sub0, sub1, (u32)t, (u32)(t + 512), o0, o1);
    sk_g[t] = o0; sk_g[t + 512] = o1;
  }
#endif
}

// ---------------- K0b: stable rank -> anchor index set (16 blocks x 64, LDS float4 scan) --
__global__ void k0b_rank(const int* __restrict__ meta, const u32* __restrict__ sk_g,
                         int* __restrict__ meta_anchor) {
  __shared__ __align__(16) u32 sk_[1024];
  const int t = threadIdx.x;
#pragma unroll
  for (int i = 0; i < 16; ++i) sk_[t + 64 * i] = sk_g[t + 64 * i];
  __syncthreads();
  const int idx = blockIdx.x * 64 + t;
  const u32 mine = sk_[idx];
  const int na = meta[0];
  int rank = 0;
  const uint4* s4 = (const uint4*)sk_;
#pragma unroll 4
  for (int j = 0; j < 256; ++j) {
    const uint4 v = s4[j];
    const int m = j * 4;
    rank += (v.x < mine || (v.x == mine && m < idx));
    rank += (v.y < mine || (v.y == mine && m + 1 < idx));
    rank += (v.z < mine || (v.z == mine && m + 2 < idx));
    rank += (v.w < mine || (v.w == mine && m + 3 < idx));
  }
  if (rank < na) meta_anchor[rank] = idx;
}

// ---------------- patch load: lane holds e = c*256 + (lane>>2)*16 + (lane&3)*4 + [0..3] ---
__device__ __forceinline__ void load_patch(const float* __restrict__ img, int n, int ph, int pw,
                                           int lane, float4 v[3]) {
  const int py = lane >> 2;
  const int px = (lane & 3) << 2;
  const float* b = img + (size_t)n * 786432 + (size_t)(ph * 16 + py) * 512 + pw * 16 + px;
#pragma unroll
  for (int c = 0; c < 3; ++c)
    v[c] = *reinterpret_cast<const float4*>(b + (size_t)c * 262144);
}

__device__ __forceinline__ float wred(float v) {
#pragma unroll
  for (int k = 32; k >= 1; k >>= 1) v += __shfl_xor(v, k);
  return v;
}

__device__ __forceinline__ float red4(float a0, float a1, float a2, float a3, int lane) {
  a0 += __shfl_xor(a0, 32); a0 += __shfl_xor(a0, 16);
  a1 += __shfl_xor(a1, 32); a1 += __shfl_xor(a1, 16);
  a2 += __shfl_xor(a2, 32); a2 += __shfl_xor(a2, 16);
  a3 += __shfl_xor(a3, 32); a3 += __shfl_xor(a3, 16);
  const int g = lane >> 4;
  float v = g == 0 ? a0 : (g == 1 ? a1 : (g == 2 ? a2 : a3));
  v += __shfl_xor(v, 8);
  v += __shfl_xor(v, 4);
  v += __shfl_xor(v, 2);
  v += __shfl_xor(v, 1);
  return v;
}

__device__ __forceinline__ float sum4(float4 a) { return a.x + a.y + a.z + a.w; }

// ---------------- K2: normalize anchors -> bf16 A-frags (global) + sumA ----------------
// A-frag layout for mfma_f32_16x16x32_bf16: slot (n,mt,kk): lane = g*16+row holds
// pn[anchor=mt*16+row][e = kk*32 + g*8 + 0..7]. Pad rows (a>=na) are zero => sim==0, safe.
__global__ void k2_anchor(const float* __restrict__ img, const int* __restrict__ meta,
                          float* __restrict__ sumA, ushort* __restrict__ fragA) {
  __shared__ __align__(16) float pns[4][768];
  const int lane = threadIdx.x & 63;
  const int wid = threadIdx.x >> 6;
  const int wg = blockIdx.x * 4 + wid;
  const int n = wg >> 6, a = wg & 63;
  const int na = meta[0];
  const int mt = a >> 4, row = a & 15;
  const bool valid = a < na;
  if (valid) {
    const int m = meta[4 + a];
    const int ph = m >> 5, pw = m & 31;
    float4 v[3];
    load_patch(img, n, ph, pw, lane, v);
    float s = sum4(v[0]) + sum4(v[1]) + sum4(v[2]);
    s = wred(s);
    const float mu = s * (1.0f / 768.0f);
    float q = 0.0f;
#pragma unroll
    for (int c = 0; c < 3; ++c) {
      float dx = v[c].x - mu; q += dx * dx;
      dx = v[c].y - mu; q += dx * dx;
      dx = v[c].z - mu; q += dx * dx;
      dx = v[c].w - mu; q += dx * dx;
    }
    q = wred(q);
    const float inv = 1.0f / sqrtf(q);   // (std+eps) cancels under L2-normalize
    float sa = 0.0f;
    float4 o[3];
#pragma unroll
    for (int c = 0; c < 3; ++c) {
      o[c].x = (v[c].x - mu) * inv; sa += o[c].x;
      o[c].y = (v[c].y - mu) * inv; sa += o[c].y;
      o[c].z = (v[c].z - mu) * inv; sa += o[c].z;
      o[c].w = (v[c].w - mu) * inv; sa += o[c].w;
    }
    sa = wred(sa);
    float4* dst = reinterpret_cast<float4*>(pns[wid]);
    dst[lane] = o[0]; dst[lane + 64] = o[1]; dst[lane + 128] = o[2];
    if (lane == 0) sumA[n * 64 + a] = sa;
  } else {
    if (lane == 0) sumA[n * 64 + a] = 0.0f;
  }
  __syncthreads();
  // repack this anchor's 768 elems into 96 frag chunks (kk=0..23, g=0..3) of 8 bf16
#pragma unroll
  for (int it = 0; it < 2; ++it) {
    const int s = lane + it * 64;
    if (s < 96) {
      const int kk = s >> 2, g = s & 3;
      uint4 w = {0u, 0u, 0u, 0u};
      if (valid) {
        const float* src = pns[wid] + kk * 32 + g * 8;
        const float4 v0 = *(const float4*)src;
        const float4 v1 = *(const float4*)(src + 4);
        w.x = (u32)f2bf(v0.x) | ((u32)f2bf(v0.y) << 16);
        w.y = (u32)f2bf(v0.z) | ((u32)f2bf(v0.w) << 16);
        w.z = (u32)f2bf(v1.x) | ((u32)f2bf(v1.y) << 16);
        w.w = (u32)f2bf(v1.z) | ((u32)f2bf(v1.w) << 16);
      }
      *(uint4*)(fragA + ((size_t)(((n * 4 + mt) * 24 + kk) * 64) + g * 16 + row) * 8) = w;
    }
  }
}

// ---------------- K3: MFMA anchor-sim. Block = (img, 64 patches); wave = 16 patches ------
// sim(a,m) = (dot(pnA_a, raw_m) - mu_m*sum(pnA_a)) * rstd_m; bf16 dot via MFMA.
// Margin >=0.3 vs bf16 error <=2^-8 => decisions exact.
__global__ __launch_bounds__(256) void k3_mfma(const float* __restrict__ img,
                                               const ushort* __restrict__ fragA,
                                               const float* __restrict__ sumA,
                                               int* __restrict__ mask) {
  __shared__ float smu[64], srs[64];
  const int lane = threadIdx.x & 63;
  const int w = threadIdx.x >> 6;
  const int n = blockIdx.x >> 4, tile = blockIdx.x & 15;
  const int pbase = tile * 64 + w * 16;
  // phase 1: per-patch mean / rstd for this wave's 16 patches (also warms L2 for phase 2)
#pragma unroll
  for (int sg = 0; sg < 4; ++sg) {
    const int p0 = pbase + sg * 4;
    const int ph = p0 >> 5, pw0 = p0 & 31;
    float4 pv[4][3];
#pragma unroll
    for (int p = 0; p < 4; ++p) load_patch(img, n, ph, pw0 + p, lane, pv[p]);
    float s0 = sum4(pv[0][0]) + sum4(pv[0][1]) + sum4(pv[0][2]);
    float s1 = sum4(pv[1][0]) + sum4(pv[1][1]) + sum4(pv[1][2]);
    float s2 = sum4(pv[2][0]) + sum4(pv[2][1]) + sum4(pv[2][2]);
    float s3 = sum4(pv[3][0]) + sum4(pv[3][1]) + sum4(pv[3][2]);
    float sv = red4(s0, s1, s2, s3, lane);
    const float mu0 = __shfl(sv, 0) * (1.0f / 768.0f);
    const float mu1 = __shfl(sv, 16) * (1.0f / 768.0f);
    const float mu2 = __shfl(sv, 32) * (1.0f / 768.0f);
    const float mu3 = __shfl(sv, 48) * (1.0f / 768.0f);
    float q0 = 0, q1 = 0, q2 = 0, q3 = 0;
#pragma unroll
    for (int c = 0; c < 3; ++c) {
      float d;
      d = pv[0][c].x - mu0; q0 += d * d; d = pv[0][c].y - mu0; q0 += d * d;
      d = pv[0][c].z - mu0; q0 += d * d; d = pv[0][c].w - mu0; q0 += d * d;
      d = pv[1][c].x - mu1; q1 += d * d; d = pv[1][c].y - mu1; q1 += d * d;
      d = pv[1][c].z - mu1; q1 += d * d; d = pv[1][c].w - mu1; q1 += d * d;
      d = pv[2][c].x - mu2; q2 += d * d; d = pv[2][c].y - mu2; q2 += d * d;
      d = pv[2][c].z - mu2; q2 += d * d; d = pv[2][c].w - mu2; q2 += d * d;
      d = pv[3][c].x - mu3; q3 += d * d; d = pv[3][c].y - mu3; q3 += d * d;
      d = pv[3][c].z - mu3; q3 += d * d; d = pv[3][c].w - mu3; q3 += d * d;
    }
    const float qv = red4(q0, q1, q2, q3, lane);
    const int g = lane >> 4;
    if ((lane & 15) == 0) {
      const float mug = g == 0 ? mu0 : (g == 1 ? mu1 : (g == 2 ? mu2 : mu3));
      smu[w * 16 + sg * 4 + g] = mug;
      srs[w * 16 + sg * 4 + g] = 1.0f / sqrtf(qv);
    }
  }
  __syncthreads();
  // phase 2: GEMM. B-frag: col c = lane&15 -> patch pbase+c; k-group g = lane>>4.
  const int c = lane & 15, g = lane >> 4;
  const int p = pbase + c;
  const int ph = p >> 5, pw = p & 31;
  const float* imgn = img + (size_t)n * 786432;
  f32x4 acc[4];
#pragma unroll
  for (int mt = 0; mt < 4; ++mt) acc[mt] = (f32x4){0.f, 0.f, 0.f, 0.f};
  const ushort* fbase = fragA + (size_t)(n * 4) * 24 * 512;
  for (int kk = 0; kk < 24; ++kk) {
    const int e0 = kk * 32 + g * 8;
    const int cch = e0 >> 8, rem = e0 & 255, py = rem >> 4, px = rem & 15;
    const float* bsrc = imgn + (size_t)cch * 262144 + (size_t)(ph * 16 + py) * 512 + pw * 16 + px;
    const float4 b0 = *(const float4*)bsrc;
    const float4 b1 = *(const float4*)(bsrc + 4);
    bf16x8 bf;
    bf[0] = (short)f2bf(b0.x); bf[1] = (short)f2bf(b0.y);
    bf[2] = (short)f2bf(b0.z); bf[3] = (short)f2bf(b0.w);
    bf[4] = (short)f2bf(b1.x); bf[5] = (short)f2bf(b1.y);
    bf[6] = (short)f2bf(b1.z); bf[7] = (short)f2bf(b1.w);
#pragma unroll
    for (int mt = 0; mt < 4; ++mt) {
      const bf16x8 af = *(const bf16x8*)(fbase + ((size_t)(mt * 24 + kk) * 64 + lane) * 8);
      acc[mt] = __builtin_amdgcn_mfma_f32_16x16x32_bf16(af, bf, acc[mt], 0, 0, 0);
    }
  }
  // epilogue: D[row][col]: col = lane&15, row(mt) = mt*16 + g*4 + i  [m89-verified C/D]
  const float mu_c = smu[w * 16 + c];
  const float rs_c = srs[w * 16 + c];
  int fl = 0;
#pragma unroll
  for (int mt = 0; mt < 4; ++mt) {
    const float4 s4 = *(const float4*)(sumA + n * 64 + mt * 16 + g * 4);
    float sim;
    sim = (acc[mt][0] - mu_c * s4.x) * rs_c; fl |= (sim > 0.5f) ? 1 : 0;
    sim = (acc[mt][1] - mu_c * s4.y) * rs_c; fl |= (sim > 0.5f) ? 1 : 0;
    sim = (acc[mt][2] - mu_c * s4.z) * rs_c; fl |= (sim > 0.5f) ? 1 : 0;
    sim = (acc[mt][3] - mu_c * s4.w) * rs_c; fl |= (sim > 0.5f) ? 1 : 0;
  }
  fl |= __shfl_xor(fl, 16);
  fl |= __shfl_xor(fl, 32);
  if (lane < 16) mask[n * 1024 + p] = fl;
}

// ---------------- K4: inline uniforms + in-block count + LDS-float4 stable rank ----------
__global__ void k4_final(const int* __restrict__ meta, const int* __restrict__ mask,
                         int* __restrict__ out) {
  __shared__ __align__(16) float ks_[1024];
  __shared__ int cnt_s;
  const int nimg = blockIdx.x >> 2, seg = blockIdx.x & 3, t = threadIdx.x;
  if (t == 0) cnt_s = 0;
  __syncthreads();
  const u32 k0 = (u32)meta[1], k1 = (u32)meta[2];
  const int base = nimg * 1024;
  const float INF = __int_as_float(0x7f800000);
  int local = 0;
#pragma unroll
  for (int i = 0; i < 4; ++i) {
    const int j = t + 256 * i;
    const int gi = base + j;
    const int mk = mask[gi];
    u32 o0, o1; float u;
#if TF_PART
    tf2x32(k0, k1, 0u, (u32)gi, o0, o1);
    u = bits_to_unit(o0 ^ o1);
#else
    if (gi < 16384) { tf2x32(k0, k1, (u32)gi, (u32)(gi + 16384), o0, o1); u = bits_to_unit(o0); }
    else            { tf2x32(k0, k1, (u32)(gi - 16384), (u32)gi, o0, o1); u = bits_to_unit(o1); }
#endif
    ks_[j] = mk ? INF : u;
    local += mk;
  }
#pragma unroll
  for (int k = 32; k >= 1; k >>= 1) local += __shfl_xor(local, k);
  if ((t & 63) == 0) atomicAdd(&cnt_s, local);
  __syncthreads();
  const int cnt = cnt_s;
  const int nadd = cnt < 512 ? (512 - cnt) : 0;  // floor((0.5-cnt/1024)*1024) exactly
  const int l = seg * 256 + t;
  const float kl = ks_[l];
  const int mk_l = mask[base + l];
  int rank = 0;
  const float4* s4 = (const float4*)ks_;
#pragma unroll 4
  for (int j = 0; j < 256; ++j) {
    const float4 v = s4[j];
    const int m = j * 4;
    rank += (v.x < kl || (v.x == kl && m < l));
    rank += (v.y < kl || (v.y == kl && m + 1 < l));
    rank += (v.z < kl || (v.z == kl && m + 2 < l));
    rank += (v.w < kl || (v.w == kl && m + 3 < l));
  }
  out[base + l] = (mk_l || rank < nadd) ? 1 : 0;
}

extern "C" void kernel_launch(void* const* d_in, const int* in_sizes, int n_in,
                              void* d_out, int out_size, void* d_ws, size_t ws_size,
                              hipStream_t stream) {
  const float* img = (const float*)d_in[0];
  const int* pct = (const int*)d_in[1];
  char* ws = (char*)d_ws;
  int* meta = (int*)(ws + META_OFF);
  u32* sk_g = (u32*)(ws + SK_OFF);
  int* mask = (int*)(ws + MASK_OFF);
  float* sumA = (float*)(ws + SUMA_OFF);
  ushort* fragA = (ushort*)(ws + FRAG_OFF);
  int* out = (int*)d_out;

  hipLaunchKernelGGL(k0a_setup, dim3(1), dim3(1024), 0, stream, pct, meta, sk_g);
  hipLaunchKernelGGL(k0b_rank, dim3(16), dim3(64), 0, stream, meta, sk_g, meta + 4);
  hipLaunchKernelGGL(k2_anchor, dim3(512), dim3(256), 0, stream, img, meta, sumA, fragA);
  hipLaunchKernelGGL(k3_mfma, dim3(512), dim3(256), 0, stream, img, fragA, sumA, mask);
  hipLaunchKernelGGL(k4_final, dim3(128), dim3(256), 0, stream, meta, mask, out);
}

// Round 8
// 207.277 us; speedup vs baseline: 1.8214x; 1.0721x over previous
//
#include <hip/hip_runtime.h>

typedef unsigned int u32;
typedef __attribute__((ext_vector_type(8))) short bf16x8;   // 8 bf16 = 4 VGPR (guide-verified)
typedef __attribute__((ext_vector_type(4))) float f32x4;

// JAX PRNG flavor: 1 = threefry_partitionable. Rounds 4/5: bit-exact. Keep 1.
#define TF_PART 1

// workspace byte offsets (total ~3.3 MB)
#define META_OFF 0                         // int: [0]=na, [1..2]=k_add, [4..67]=anchor idx
#define SK_OFF   4096                      // u32 sk[1024]
#define MASK_OFF 16384                     // int mask[32*1024] = 128 KB
#define SUMA_OFF (MASK_OFF + 131072)       // float sumA[32][64]
#define FRAG_OFF (SUMA_OFF + 32*64*4)      // bf16 fragA[(n*4+mt)*24+kk][64 lanes][8] = 3 MB

// ---------------- threefry2x32 (matches jax._src.prng.threefry2x32) ----------------
__device__ __forceinline__ void tf2x32(u32 k0, u32 k1, u32 x0, u32 x1, u32& o0, u32& o1) {
  const u32 ks2 = k0 ^ k1 ^ 0x1BD11BDAu;
  u32 v0 = x0 + k0, v1 = x1 + k1;
#define TFR(r) { v0 += v1; v1 = (v1 << (r)) | (v1 >> (32 - (r))); v1 ^= v0; }
  TFR(13) TFR(15) TFR(26) TFR(6)   v0 += k1;  v1 += ks2 + 1u;
  TFR(17) TFR(29) TFR(16) TFR(24)  v0 += ks2; v1 += k0 + 2u;
  TFR(13) TFR(15) TFR(26) TFR(6)   v0 += k0;  v1 += k1 + 3u;
  TFR(17) TFR(29) TFR(16) TFR(24)  v0 += k1;  v1 += ks2 + 4u;
  TFR(13) TFR(15) TFR(26) TFR(6)   v0 += ks2; v1 += k0 + 5u;
#undef TFR
  o0 = v0; o1 = v1;
}

__device__ __forceinline__ float bits_to_unit(u32 b) {
  return __uint_as_float((b >> 9) | 0x3f800000u) - 1.0f;
}

__device__ __forceinline__ ushort f2bf(float f) {   // RNE fp32->bf16
  u32 b = __float_as_uint(f);
  return (ushort)((b + 0x7fffu + ((b >> 16) & 1u)) >> 16);
}

// ---------------- K0a: meta (na, k_add) + permutation sort-keys -> global ----------------
// thr is NOT computed: sim[l,l]=||pn_l||^2=1 in fp32 and all bsearch midpoints <1 =>
// ratio==1 every step => best_t = first midpoint = 0.5 for any target.
__global__ void k0a_setup(const int* __restrict__ pct, int* __restrict__ meta,
                          u32* __restrict__ sk_g) {
  __shared__ u32 sub0, sub1;
  const int t = threadIdx.x;
  if (t == 0) {
    u32 ka0, ka1, kb0, kb1, s0, s1;
#if TF_PART
    tf2x32(0u, 42u, 0u, 0u, ka0, ka1);   // k_anchor = split(key(42))[0]
    tf2x32(0u, 42u, 0u, 1u, kb0, kb1);   // k_add    = split(key(42))[1]
    tf2x32(ka0, ka1, 0u, 1u, s0, s1);    // shuffle subkey = split(k_anchor)[1]
#else
    u32 a, b, c, d;
    tf2x32(0u, 42u, 0u, 2u, a, b);
    tf2x32(0u, 42u, 1u, 3u, c, d);
    ka0 = a; ka1 = c; kb0 = b; kb1 = d;
    tf2x32(ka0, ka1, 0u, 2u, a, b);
    tf2x32(ka0, ka1, 1u, 3u, c, d);
    s0 = b; s1 = d;
#endif
    meta[1] = (int)kb0; meta[2] = (int)kb1;
    sub0 = s0; sub1 = s1;
    const int p = pct[0];
    int na = (int)(1024.0 * ((double)p / 100.0) * 0.05);  // int(L*mask_ratio*0.05)
    if (na < 1) na = 1;
    if (na > 64) na = 64;
    meta[0] = na;
  }
  __syncthreads();
#if TF_PART
  { u32 o0, o1; tf2x32(sub0, sub1, 0u, (u32)t, o0, o1); sk_g[t] = o0 ^ o1; }
#else
  if (t < 512) {
    u32 o0, o1; tf2x32(sub0, sub1, (u32)t, (u32)(t + 512), o0, o1);
    sk_g[t] = o0; sk_g[t + 512] = o1;
  }
#endif
}

// ---------------- K0b: stable rank -> anchor index set (16 blocks x 64, LDS float4 scan) --
__global__ void k0b_rank(const int* __restrict__ meta, const u32* __restrict__ sk_g,
                         int* __restrict__ meta_anchor) {
  __shared__ __align__(16) u32 sk_[1024];
  const int t = threadIdx.x;
#pragma unroll
  for (int i = 0; i < 16; ++i) sk_[t + 64 * i] = sk_g[t + 64 * i];
  __syncthreads();
  const int idx = blockIdx.x * 64 + t;
  const u32 mine = sk_[idx];
  const int na = meta[0];
  int rank = 0;
  const uint4* s4 = (const uint4*)sk_;
#pragma unroll 4
  for (int j = 0; j < 256; ++j) {
    const uint4 v = s4[j];
    const int m = j * 4;
    rank += (v.x < mine || (v.x == mine && m < idx));
    rank += (v.y < mine || (v.y == mine && m + 1 < idx));
    rank += (v.z < mine || (v.z == mine && m + 2 < idx));
    rank += (v.w < mine || (v.w == mine && m + 3 < idx));
  }
  if (rank < na) meta_anchor[rank] = idx;
}

// ---------------- patch load: lane holds e = c*256 + (lane>>2)*16 + (lane&3)*4 + [0..3] ---
__device__ __forceinline__ void load_patch(const float* __restrict__ img, int n, int ph, int pw,
                                           int lane, float4 v[3]) {
  const int py = lane >> 2;
  const int px = (lane & 3) << 2;
  const float* b = img + (size_t)n * 786432 + (size_t)(ph * 16 + py) * 512 + pw * 16 + px;
#pragma unroll
  for (int c = 0; c < 3; ++c)
    v[c] = *reinterpret_cast<const float4*>(b + (size_t)c * 262144);
}

__device__ __forceinline__ float wred(float v) {
#pragma unroll
  for (int k = 32; k >= 1; k >>= 1) v += __shfl_xor(v, k);
  return v;
}

__device__ __forceinline__ float sum4(float4 a) { return a.x + a.y + a.z + a.w; }

// ---------------- K2: normalize anchors -> bf16 A-frags (global) + sumA ----------------
// A-frag layout for mfma_f32_16x16x32_bf16: slot (n,mt,kk): lane = g*16+row holds
// pn[anchor=mt*16+row][e = kk*32 + g*8 + 0..7]. Pad rows (a>=na) are zero => sim==0, safe.
__global__ void k2_anchor(const float* __restrict__ img, const int* __restrict__ meta,
                          float* __restrict__ sumA, ushort* __restrict__ fragA) {
  __shared__ __align__(16) float pns[4][768];
  const int lane = threadIdx.x & 63;
  const int wid = threadIdx.x >> 6;
  const int wg = blockIdx.x * 4 + wid;
  const int n = wg >> 6, a = wg & 63;
  const int na = meta[0];
  const int mt = a >> 4, row = a & 15;
  const bool valid = a < na;
  if (valid) {
    const int m = meta[4 + a];
    const int ph = m >> 5, pw = m & 31;
    float4 v[3];
    load_patch(img, n, ph, pw, lane, v);
    float s = sum4(v[0]) + sum4(v[1]) + sum4(v[2]);
    s = wred(s);
    const float mu = s * (1.0f / 768.0f);
    float q = 0.0f;
#pragma unroll
    for (int c = 0; c < 3; ++c) {
      float dx = v[c].x - mu; q += dx * dx;
      dx = v[c].y - mu; q += dx * dx;
      dx = v[c].z - mu; q += dx * dx;
      dx = v[c].w - mu; q += dx * dx;
    }
    q = wred(q);
    const float inv = 1.0f / sqrtf(q);   // (std+eps) cancels under L2-normalize
    float sa = 0.0f;
    float4 o[3];
#pragma unroll
    for (int c = 0; c < 3; ++c) {
      o[c].x = (v[c].x - mu) * inv; sa += o[c].x;
      o[c].y = (v[c].y - mu) * inv; sa += o[c].y;
      o[c].z = (v[c].z - mu) * inv; sa += o[c].z;
      o[c].w = (v[c].w - mu) * inv; sa += o[c].w;
    }
    sa = wred(sa);
    float4* dst = reinterpret_cast<float4*>(pns[wid]);
    dst[lane] = o[0]; dst[lane + 64] = o[1]; dst[lane + 128] = o[2];
    if (lane == 0) sumA[n * 64 + a] = sa;
  } else {
    if (lane == 0) sumA[n * 64 + a] = 0.0f;
  }
  __syncthreads();
  // repack this anchor's 768 elems into 96 frag chunks (kk=0..23, g=0..3) of 8 bf16
#pragma unroll
  for (int it = 0; it < 2; ++it) {
    const int s = lane + it * 64;
    if (s < 96) {
      const int kk = s >> 2, g = s & 3;
      uint4 w = {0u, 0u, 0u, 0u};
      if (valid) {
        const float* src = pns[wid] + kk * 32 + g * 8;
        const float4 v0 = *(const float4*)src;
        const float4 v1 = *(const float4*)(src + 4);
        w.x = (u32)f2bf(v0.x) | ((u32)f2bf(v0.y) << 16);
        w.y = (u32)f2bf(v0.z) | ((u32)f2bf(v0.w) << 16);
        w.z = (u32)f2bf(v1.x) | ((u32)f2bf(v1.y) << 16);
        w.w = (u32)f2bf(v1.z) | ((u32)f2bf(v1.w) << 16);
      }
      *(uint4*)(fragA + ((size_t)(((n * 4 + mt) * 24 + kk) * 64) + g * 16 + row) * 8) = w;
    }
  }
}

// ---------------- K3: single-pass MFMA anchor-sim (stats fused into GEMM loop) -----------
// sim(a,m) = (dot(pnA_a, raw_m) - mu_m*sum(pnA_a)) * rstd_m.
// Lane (c,g) streams the 192 elements e=kk*32+g*8+0..7 of patch pbase+c exactly once:
// accumulates s=sum(v), q=sum(v^2) (fp32) AND feeds bf16 B-frags to MFMA. After the loop,
// shfl_xor(16,32) combines the 4 k-groups; ssq_centered = q - s^2/768 (rel err ~1e-5 vs
// decision margin >=0.3). No phase-1 img pass, no LDS, no syncthreads -> img read ONCE.
__global__ __launch_bounds__(256) void k3_mfma(const float* __restrict__ img,
                                               const ushort* __restrict__ fragA,
                                               const float* __restrict__ sumA,
                                               int* __restrict__ mask) {
  const int lane = threadIdx.x & 63;
  const int w = threadIdx.x >> 6;
  const int n = blockIdx.x >> 4, tile = blockIdx.x & 15;
  const int pbase = tile * 64 + w * 16;
  const int c = lane & 15, g = lane >> 4;
  const int p = pbase + c;
  const int ph = p >> 5, pw = p & 31;
  const float* imgn = img + (size_t)n * 786432;
  f32x4 a0 = {0.f, 0.f, 0.f, 0.f}, a1 = {0.f, 0.f, 0.f, 0.f};
  f32x4 a2 = {0.f, 0.f, 0.f, 0.f}, a3 = {0.f, 0.f, 0.f, 0.f};
  float s = 0.0f, q = 0.0f;
  const ushort* fbase = fragA + (size_t)(n * 4) * 24 * 512;
#pragma unroll 4
  for (int kk = 0; kk < 24; ++kk) {
    const int e0 = kk * 32 + g * 8;
    const int cch = e0 >> 8, rem = e0 & 255, py = rem >> 4, px = rem & 15;
    const float* bsrc = imgn + (size_t)cch * 262144 + (size_t)(ph * 16 + py) * 512 + pw * 16 + px;
    const float4 b0 = *(const float4*)bsrc;
    const float4 b1 = *(const float4*)(bsrc + 4);
    s += b0.x + b0.y + b0.z + b0.w + b1.x + b1.y + b1.z + b1.w;
    q = fmaf(b0.x, b0.x, q); q = fmaf(b0.y, b0.y, q);
    q = fmaf(b0.z, b0.z, q); q = fmaf(b0.w, b0.w, q);
    q = fmaf(b1.x, b1.x, q); q = fmaf(b1.y, b1.y, q);
    q = fmaf(b1.z, b1.z, q); q = fmaf(b1.w, b1.w, q);
    bf16x8 bf;
    bf[0] = (short)f2bf(b0.x); bf[1] = (short)f2bf(b0.y);
    bf[2] = (short)f2bf(b0.z); bf[3] = (short)f2bf(b0.w);
    bf[4] = (short)f2bf(b1.x); bf[5] = (short)f2bf(b1.y);
    bf[6] = (short)f2bf(b1.z); bf[7] = (short)f2bf(b1.w);
    const ushort* fk = fbase + (size_t)kk * 512 + (size_t)lane * 8;
    const bf16x8 af0 = *(const bf16x8*)(fk);
    const bf16x8 af1 = *(const bf16x8*)(fk + 24 * 512);
    const bf16x8 af2 = *(const bf16x8*)(fk + 48 * 512);
    const bf16x8 af3 = *(const bf16x8*)(fk + 72 * 512);
    a0 = __builtin_amdgcn_mfma_f32_16x16x32_bf16(af0, bf, a0, 0, 0, 0);
    a1 = __builtin_amdgcn_mfma_f32_16x16x32_bf16(af1, bf, a1, 0, 0, 0);
    a2 = __builtin_amdgcn_mfma_f32_16x16x32_bf16(af2, bf, a2, 0, 0, 0);
    a3 = __builtin_amdgcn_mfma_f32_16x16x32_bf16(af3, bf, a3, 0, 0, 0);
  }
  // combine the 4 k-group partial stats of column c
  s += __shfl_xor(s, 16); s += __shfl_xor(s, 32);
  q += __shfl_xor(q, 16); q += __shfl_xor(q, 32);
  const float mu_c = s * (1.0f / 768.0f);
  const float qc = q - s * s * (1.0f / 768.0f);   // == sum((v-mu)^2), margin-safe
  const float rs_c = 1.0f / sqrtf(qc);
  // epilogue: D[row][col]: col = lane&15, row(mt) = mt*16 + g*4 + i  [m89-verified C/D]
  int fl = 0;
#pragma unroll
  for (int mt = 0; mt < 4; ++mt) {
    const f32x4 acc = mt == 0 ? a0 : (mt == 1 ? a1 : (mt == 2 ? a2 : a3));
    const float4 s4 = *(const float4*)(sumA + n * 64 + mt * 16 + g * 4);
    float sim;
    sim = (acc[0] - mu_c * s4.x) * rs_c; fl |= (sim > 0.5f) ? 1 : 0;
    sim = (acc[1] - mu_c * s4.y) * rs_c; fl |= (sim > 0.5f) ? 1 : 0;
    sim = (acc[2] - mu_c * s4.z) * rs_c; fl |= (sim > 0.5f) ? 1 : 0;
    sim = (acc[3] - mu_c * s4.w) * rs_c; fl |= (sim > 0.5f) ? 1 : 0;
  }
  fl |= __shfl_xor(fl, 16);
  fl |= __shfl_xor(fl, 32);
  if (lane < 16) mask[n * 1024 + p] = fl;
}

// ---------------- K4: inline uniforms + in-block count + LDS-float4 stable rank ----------
__global__ void k4_final(const int* __restrict__ meta, const int* __restrict__ mask,
                         int* __restrict__ out) {
  __shared__ __align__(16) float ks_[1024];
  __shared__ int cnt_s;
  const int nimg = blockIdx.x >> 2, seg = blockIdx.x & 3, t = threadIdx.x;
  if (t == 0) cnt_s = 0;
  __syncthreads();
  const u32 k0 = (u32)meta[1], k1 = (u32)meta[2];
  const int base = nimg * 1024;
  const float INF = __int_as_float(0x7f800000);
  int local = 0;
#pragma unroll
  for (int i = 0; i < 4; ++i) {
    const int j = t + 256 * i;
    const int gi = base + j;
    const int mk = mask[gi];
    u32 o0, o1; float u;
#if TF_PART
    tf2x32(k0, k1, 0u, (u32)gi, o0, o1);
    u = bits_to_unit(o0 ^ o1);
#else
    if (gi < 16384) { tf2x32(k0, k1, (u32)gi, (u32)(gi + 16384), o0, o1); u = bits_to_unit(o0); }
    else            { tf2x32(k0, k1, (u32)(gi - 16384), (u32)gi, o0, o1); u = bits_to_unit(o1); }
#endif
    ks_[j] = mk ? INF : u;
    local += mk;
  }
#pragma unroll
  for (int k = 32; k >= 1; k >>= 1) local += __shfl_xor(local, k);
  if ((t & 63) == 0) atomicAdd(&cnt_s, local);
  __syncthreads();
  const int cnt = cnt_s;
  const int nadd = cnt < 512 ? (512 - cnt) : 0;  // floor((0.5-cnt/1024)*1024) exactly
  const int l = seg * 256 + t;
  const float kl = ks_[l];
  const int mk_l = mask[base + l];
  int rank = 0;
  const float4* s4 = (const float4*)ks_;
#pragma unroll 4
  for (int j = 0; j < 256; ++j) {
    const float4 v = s4[j];
    const int m = j * 4;
    rank += (v.x < kl || (v.x == kl && m < l));
    rank += (v.y < kl || (v.y == kl && m + 1 < l));
    rank += (v.z < kl || (v.z == kl && m + 2 < l));
    rank += (v.w < kl || (v.w == kl && m + 3 < l));
  }
  out[base + l] = (mk_l || rank < nadd) ? 1 : 0;
}

extern "C" void kernel_launch(void* const* d_in, const int* in_sizes, int n_in,
                              void* d_out, int out_size, void* d_ws, size_t ws_size,
                              hipStream_t stream) {
  const float* img = (const float*)d_in[0];
  const int* pct = (const int*)d_in[1];
  char* ws = (char*)d_ws;
  int* meta = (int*)(ws + META_OFF);
  u32* sk_g = (u32*)(ws + SK_OFF);
  int* mask = (int*)(ws + MASK_OFF);
  float* sumA = (float*)(ws + SUMA_OFF);
  ushort* fragA = (ushort*)(ws + FRAG_OFF);
  int* out = (int*)d_out;

  hipLaunchKernelGGL(k0a_setup, dim3(1), dim3(1024), 0, stream, pct, meta, sk_g);
  hipLaunchKernelGGL(k0b_rank, dim3(16), dim3(64), 0, stream, meta, sk_g, meta + 4);
  hipLaunchKernelGGL(k2_anchor, dim3(512), dim3(256), 0, stream, img, meta, sumA, fragA);
  hipLaunchKernelGGL(k3_mfma, dim3(512), dim3(256), 0, stream, img, fragA, sumA, mask);
  hipLaunchKernelGGL(k4_final, dim3(128), dim3(256), 0, stream, meta, mask, out);
}